// Round 1
// baseline (62.492 us; speedup 1.0000x reference)
//
#include <hip/hip_runtime.h>

#define CLS 8

__device__ __forceinline__ float wave_reduce(float v) {
#pragma unroll
    for (int off = 32; off > 0; off >>= 1) v += __shfl_xor(v, off);
    return v;
}

// Streaming pass: per-pixel logsumexp (CE) + class-conditional channel sums S[b][i][k]
// and class counts n[b][k], accumulated in registers, reduced wave->LDS->global atomics.
__global__ __launch_bounds__(256) void jce_main(
    const float* __restrict__ pred, const int* __restrict__ tgt,
    float* __restrict__ S, float* __restrict__ nCnt, float* __restrict__ ceAcc,
    int N, int blocksPerBatch)
{
    const int b   = blockIdx.x / blocksPerBatch;
    const int blk = blockIdx.x % blocksPerBatch;
    const int pixelsPerBlock = N / blocksPerBatch;
    const int base = blk * pixelsPerBlock;
    const float* pb = pred + (size_t)b * CLS * N;
    const int*   tb = tgt  + (size_t)b * N;

    float acc[CLS][CLS];
    float accn[CLS];
#pragma unroll
    for (int i = 0; i < CLS; ++i) {
        accn[i] = 0.f;
#pragma unroll
        for (int k = 0; k < CLS; ++k) acc[i][k] = 0.f;
    }
    float accce = 0.f;

    const int iters = pixelsPerBlock / (256 * 4);
    for (int it = 0; it < iters; ++it) {
        const int pix = base + ((it << 8) + (int)threadIdx.x) * 4;
        float4 p4[CLS];
#pragma unroll
        for (int i = 0; i < CLS; ++i)
            p4[i] = *reinterpret_cast<const float4*>(pb + (size_t)i * N + pix);
        const int4 t4 = *reinterpret_cast<const int4*>(tb + pix);
        const float* pv  = reinterpret_cast<const float*>(p4);
        const int*   tv4 = reinterpret_cast<const int*>(&t4);

#pragma unroll
        for (int e = 0; e < 4; ++e) {
            float pc[CLS];
#pragma unroll
            for (int i = 0; i < CLS; ++i) pc[i] = pv[i * 4 + e];
            const int tv = tv4[e];

            // logsumexp over channels
            float m = pc[0];
#pragma unroll
            for (int i = 1; i < CLS; ++i) m = fmaxf(m, pc[i]);
            float s = 0.f;
#pragma unroll
            for (int i = 0; i < CLS; ++i) s += exp2f((pc[i] - m) * 1.442695040888963f);
            const float lse = m + log2f(s) * 0.693147180559945f;

            float picked = 0.f;
#pragma unroll
            for (int k = 0; k < CLS; ++k) {
                const float pm = (tv == k) ? 1.0f : 0.0f;
                accn[k] += pm;
                picked = fmaf(pm, pc[k], picked);
#pragma unroll
                for (int i = 0; i < CLS; ++i) acc[i][k] = fmaf(pm, pc[i], acc[i][k]);
            }
            accce += picked - lse;
        }
    }

    // Reduce 73 partials: wave shuffle -> LDS (per wave) -> 1 atomic per entry per block
    __shared__ float red[4][73];
    const int wave = threadIdx.x >> 6;
    const int lane = threadIdx.x & 63;

#pragma unroll
    for (int i = 0; i < CLS; ++i) {
#pragma unroll
        for (int k = 0; k < CLS; ++k) {
            const float v = wave_reduce(acc[i][k]);
            if (lane == 0) red[wave][i * 8 + k] = v;
        }
    }
#pragma unroll
    for (int k = 0; k < CLS; ++k) {
        const float v = wave_reduce(accn[k]);
        if (lane == 0) red[wave][64 + k] = v;
    }
    {
        const float v = wave_reduce(accce);
        if (lane == 0) red[wave][72] = v;
    }
    __syncthreads();

    if (threadIdx.x < 73) {
        const float v = red[0][threadIdx.x] + red[1][threadIdx.x]
                      + red[2][threadIdx.x] + red[3][threadIdx.x];
        if (threadIdx.x < 64)      atomicAdd(&S[b * 64 + (int)threadIdx.x], v);
        else if (threadIdx.x < 72) atomicAdd(&nCnt[b * 8 + ((int)threadIdx.x - 64)], v);
        else                       atomicAdd(ceAcc, v);
    }
}

// Epilogue: A = S/n, j[b] = -sum_{i!=k} w[i,k]*log(0.5 + 0.5*(A[i,i]-A[i,k])), out = j + ce
__global__ __launch_bounds__(64) void jce_final(
    const float* __restrict__ S, const float* __restrict__ nCnt,
    const float* __restrict__ ceAcc, const float* __restrict__ w,
    float* __restrict__ out, int B, int N)
{
    const int b   = blockIdx.x;
    const int tid = threadIdx.x;         // 64 threads = 1 wave
    const int i = tid >> 3, k = tid & 7;

    const float A = S[b * 64 + tid] / nCnt[b * 8 + k];
    __shared__ float lA[64];
    lA[tid] = A;
    __syncthreads();
    const float diag = lA[i * 8 + i];

    float term = 0.f;
    if (i != k)
        term = w[tid] * (log2f(0.5f + 0.5f * (diag - A)) * 0.693147180559945f);

#pragma unroll
    for (int off = 32; off > 0; off >>= 1) term += __shfl_xor(term, off);

    if (tid == 0) {
        const float ce = -ceAcc[0] / ((float)B * (float)N);
        out[b] = -term + ce;
    }
}

extern "C" void kernel_launch(void* const* d_in, const int* in_sizes, int n_in,
                              void* d_out, int out_size, void* d_ws, size_t ws_size,
                              hipStream_t stream) {
    const float* pred = (const float*)d_in[0];
    const int*   tgt  = (const int*)d_in[1];
    const float* w    = (const float*)d_in[2];
    float* out = (float*)d_out;

    const int B = out_size;               // 8
    const int N = in_sizes[1] / B;        // H*W = 262144

    float* S     = (float*)d_ws;          // B*64
    float* nCnt  = S + (size_t)B * 64;    // B*8
    float* ceAcc = nCnt + (size_t)B * 8;  // 1

    hipMemsetAsync(d_ws, 0, (size_t)(B * 64 + B * 8 + 1) * sizeof(float), stream);

    const int blocksPerBatch = 128;       // 1024 blocks total, 2048 px/block, 2 float4 iters/thread
    jce_main<<<dim3(B * blocksPerBatch), dim3(256), 0, stream>>>(
        pred, tgt, S, nCnt, ceAcc, N, blocksPerBatch);
    jce_final<<<dim3(B), dim3(64), 0, stream>>>(S, nCnt, ceAcc, w, out, B, N);
}

// Round 2
// 45.018 us; speedup vs baseline: 1.3882x; 1.3882x over previous
//
#include <hip/hip_runtime.h>

#define CLS 8
#define BPB 64   // blocks per batch -> 512 blocks, 4096 px/block, 4 float4-iters/thread

__device__ __forceinline__ float wave_reduce(float v) {
#pragma unroll
    for (int off = 32; off > 0; off >>= 1) v += __shfl_xor(v, off);
    return v;
}

struct Payload {
    float4 p[CLS];
    int4   t;
};

__global__ __launch_bounds__(256) void jce_main(
    const float* __restrict__ pred, const int* __restrict__ tgt,
    float* __restrict__ S, float* __restrict__ nCnt, float* __restrict__ ceAcc,
    int N)
{
    const int b   = blockIdx.x / BPB;
    const int blk = blockIdx.x % BPB;
    const int pixelsPerBlock = N / BPB;
    const int base = blk * pixelsPerBlock;
    const int tid  = threadIdx.x;
    const float* pb = pred + (size_t)b * CLS * N;
    const int*   tb = tgt  + (size_t)b * N;

    float acc[CLS][CLS];
    float accn[CLS];
#pragma unroll
    for (int i = 0; i < CLS; ++i) {
        accn[i] = 0.f;
#pragma unroll
        for (int k = 0; k < CLS; ++k) acc[i][k] = 0.f;
    }
    float accce = 0.f;

    const int iters = pixelsPerBlock / (256 * 4);

#define LOADP(buf, it) do {                                                        \
        const int _pix = base + ((((it) << 8)) + tid) * 4;                         \
        _Pragma("unroll")                                                          \
        for (int _i = 0; _i < CLS; ++_i)                                           \
            (buf).p[_i] = *reinterpret_cast<const float4*>(pb + (size_t)_i * N + _pix); \
        (buf).t = *reinterpret_cast<const int4*>(tb + _pix);                       \
    } while (0)

#define COMPUTEP(buf) do {                                                         \
        const float* _pv = reinterpret_cast<const float*>((buf).p);                \
        const int*   _tv = reinterpret_cast<const int*>(&(buf).t);                 \
        _Pragma("unroll")                                                          \
        for (int _e = 0; _e < 4; ++_e) {                                           \
            float _pc[CLS];                                                        \
            _Pragma("unroll")                                                      \
            for (int _i = 0; _i < CLS; ++_i) _pc[_i] = _pv[_i * 4 + _e];           \
            const int _t = _tv[_e];                                                \
            float _m01 = fmaxf(_pc[0], _pc[1]), _m23 = fmaxf(_pc[2], _pc[3]);      \
            float _m45 = fmaxf(_pc[4], _pc[5]), _m67 = fmaxf(_pc[6], _pc[7]);      \
            float _m = fmaxf(fmaxf(_m01, _m23), fmaxf(_m45, _m67));                \
            float _s = 0.f;                                                        \
            _Pragma("unroll")                                                      \
            for (int _i = 0; _i < CLS; ++_i)                                       \
                _s += exp2f((_pc[_i] - _m) * 1.442695040888963f);                  \
            const float _lse = _m + log2f(_s) * 0.693147180559945f;                \
            float _picked = 0.f;                                                   \
            _Pragma("unroll")                                                      \
            for (int _k = 0; _k < CLS; ++_k) {                                     \
                const float _pm = (_t == _k) ? 1.0f : 0.0f;                        \
                accn[_k] += _pm;                                                   \
                _picked = fmaf(_pm, _pc[_k], _picked);                             \
                _Pragma("unroll")                                                  \
                for (int _i = 0; _i < CLS; ++_i)                                   \
                    acc[_i][_k] = fmaf(_pm, _pc[_i], acc[_i][_k]);                 \
            }                                                                      \
            accce += _picked - _lse;                                               \
        }                                                                          \
    } while (0)

    Payload bufA, bufB;
    LOADP(bufA, 0);
    int it = 0;
    for (; it + 2 <= iters; it += 2) {
        LOADP(bufB, it + 1);      // prefetch while bufA's data is in flight/consumed
        COMPUTEP(bufA);
        if (it + 2 < iters) LOADP(bufA, it + 2);
        COMPUTEP(bufB);
    }
    if (it < iters) COMPUTEP(bufA);   // odd-iters tail (bufA preloaded in loop)

#undef LOADP
#undef COMPUTEP

    // Reduce 73 partials: wave shuffle -> LDS (per wave) -> 1 atomic per entry per block
    __shared__ float red[4][73];
    const int wave = tid >> 6;
    const int lane = tid & 63;

#pragma unroll
    for (int i = 0; i < CLS; ++i) {
#pragma unroll
        for (int k = 0; k < CLS; ++k) {
            const float v = wave_reduce(acc[i][k]);
            if (lane == 0) red[wave][i * 8 + k] = v;
        }
    }
#pragma unroll
    for (int k = 0; k < CLS; ++k) {
        const float v = wave_reduce(accn[k]);
        if (lane == 0) red[wave][64 + k] = v;
    }
    {
        const float v = wave_reduce(accce);
        if (lane == 0) red[wave][72] = v;
    }
    __syncthreads();

    if (tid < 73) {
        const float v = red[0][tid] + red[1][tid] + red[2][tid] + red[3][tid];
        if (tid < 64)      atomicAdd(&S[b * 64 + tid], v);
        else if (tid < 72) atomicAdd(&nCnt[b * 8 + (tid - 64)], v);
        else               atomicAdd(ceAcc, v);
    }
}

// Epilogue: A = S/n, j[b] = -sum_{i!=k} w[i,k]*log(0.5 + 0.5*(A[i,i]-A[i,k])), out = j + ce
__global__ __launch_bounds__(64) void jce_final(
    const float* __restrict__ S, const float* __restrict__ nCnt,
    const float* __restrict__ ceAcc, const float* __restrict__ w,
    float* __restrict__ out, int B, int N)
{
    const int b   = blockIdx.x;
    const int tid = threadIdx.x;         // 64 threads = 1 wave
    const int i = tid >> 3, k = tid & 7;

    const float A = S[b * 64 + tid] / nCnt[b * 8 + k];
    __shared__ float lA[64];
    lA[tid] = A;
    __syncthreads();
    const float diag = lA[i * 8 + i];

    float term = 0.f;
    if (i != k)
        term = w[tid] * (log2f(0.5f + 0.5f * (diag - A)) * 0.693147180559945f);

#pragma unroll
    for (int off = 32; off > 0; off >>= 1) term += __shfl_xor(term, off);

    if (tid == 0) {
        const float ce = -ceAcc[0] / ((float)B * (float)N);
        out[b] = -term + ce;
    }
}

extern "C" void kernel_launch(void* const* d_in, const int* in_sizes, int n_in,
                              void* d_out, int out_size, void* d_ws, size_t ws_size,
                              hipStream_t stream) {
    const float* pred = (const float*)d_in[0];
    const int*   tgt  = (const int*)d_in[1];
    const float* w    = (const float*)d_in[2];
    float* out = (float*)d_out;

    const int B = out_size;               // 8
    const int N = in_sizes[1] / B;        // H*W = 262144

    float* S     = (float*)d_ws;          // B*64
    float* nCnt  = S + (size_t)B * 64;    // B*8
    float* ceAcc = nCnt + (size_t)B * 8;  // 1

    hipMemsetAsync(d_ws, 0, (size_t)(B * 64 + B * 8 + 1) * sizeof(float), stream);

    jce_main<<<dim3(B * BPB), dim3(256), 0, stream>>>(pred, tgt, S, nCnt, ceAcc, N);
    jce_final<<<dim3(B), dim3(64), 0, stream>>>(S, nCnt, ceAcc, w, out, B, N);
}

// Round 3
// 38.591 us; speedup vs baseline: 1.6193x; 1.1665x over previous
//
#include <hip/hip_runtime.h>

#define CLS 8
#define BATCH 8
#define BPB 128                      // blocks per batch -> 1024 blocks, 2048 px/block
#define LOG2E 1.442695040888963f
#define LN2   0.693147180559945f

// select compile-time component e of a float4/int4
#define F4C(v, e) ((e) == 0 ? (v).x : (e) == 1 ? (v).y : (e) == 2 ? (v).z : (v).w)

__device__ __forceinline__ float wave_reduce(float v) {
#pragma unroll
    for (int off = 32; off > 0; off >>= 1) v += __shfl_xor(v, off);
    return v;
}

__global__ __launch_bounds__(256, 4) void jce_main(
    const float* __restrict__ pred, const int* __restrict__ tgt,
    float* __restrict__ S, float* __restrict__ nCnt, float* __restrict__ lseAcc,
    int N)
{
    const int tid  = threadIdx.x;
    const int b    = blockIdx.x & (BATCH - 1);
    const int blk  = blockIdx.x >> 3;
    const int base = blk * (N / BPB);                 // 2048 px per block
    const float* pb = pred + (size_t)b * CLS * N;
    const int*   tb = tgt  + (size_t)b * N;

    float acc[64];                                    // acc[i*8+k] = sum_{p: t=k} pred[i]
#pragma unroll
    for (int j = 0; j < 64; ++j) acc[j] = 0.f;
    float accl = 0.f;                                 // sum of log2(sum_i 2^(pc_i*log2e))
    int cnt[CLS] = {0, 0, 0, 0, 0, 0, 0, 0};          // wave-uniform class counts (SGPR)

    const int pix0 = base + tid * 4;
    const int pix1 = base + 1024 + tid * 4;

    float4 pA[CLS], pB[CLS];
    int4 tA, tB;

#define LOADP(P, T, pix) do {                                                   \
        _Pragma("unroll")                                                       \
        for (int _i = 0; _i < CLS; ++_i)                                        \
            (P)[_i] = *reinterpret_cast<const float4*>(pb + (size_t)_i * N + (pix)); \
        (T) = *reinterpret_cast<const int4*>(tb + (pix));                       \
    } while (0)

#define COMPUTE_E(P, T, e) do {                                                 \
        float _pc[CLS];                                                         \
        _Pragma("unroll")                                                       \
        for (int _i = 0; _i < CLS; ++_i) _pc[_i] = F4C((P)[_i], e);             \
        const int _t = F4C((T), e);                                             \
        float _s = 0.f;                                                         \
        _Pragma("unroll")                                                       \
        for (int _i = 0; _i < CLS; ++_i) _s += exp2f(_pc[_i] * LOG2E);          \
        accl += log2f(_s);                                                      \
        _Pragma("unroll")                                                       \
        for (int _k = 0; _k < CLS; ++_k) {                                      \
            const bool _isk = (_t == _k);                                       \
            cnt[_k] += __popcll(__ballot(_isk));                                \
            const float _pm = _isk ? 1.f : 0.f;                                 \
            _Pragma("unroll")                                                   \
            for (int _i = 0; _i < CLS; ++_i)                                    \
                acc[_i * 8 + _k] = fmaf(_pm, _pc[_i], acc[_i * 8 + _k]);        \
        }                                                                       \
    } while (0)

    LOADP(pA, tA, pix0);
    COMPUTE_E(pA, tA, 0);
    COMPUTE_E(pA, tA, 1);
    LOADP(pB, tB, pix1);              // issue 2nd payload mid-compute (latency hiding)
    COMPUTE_E(pA, tA, 2);
    COMPUTE_E(pA, tA, 3);
    COMPUTE_E(pB, tB, 0);
    COMPUTE_E(pB, tB, 1);
    COMPUTE_E(pB, tB, 2);
    COMPUTE_E(pB, tB, 3);

#undef LOADP
#undef COMPUTE_E

    // ---- split-vector butterfly: reduce 64-entry vector across 64 lanes ----
    // After 6 stages lane l holds the wave-total of entry e = bitrev6(l).
    const int lane = tid & 63;
#pragma unroll
    for (int s6 = 0; s6 < 6; ++s6) {
        const int d = 1 << s6;
        const int half = 32 >> s6;
        const bool hi = (lane & d) != 0;
#pragma unroll
        for (int j = 0; j < half; ++j) {
            const float keep = hi ? acc[j + half] : acc[j];
            const float send = hi ? acc[j] : acc[j + half];
            acc[j] = keep + __shfl_xor(send, d);
        }
    }
    const int e = ((lane & 1) << 5) | ((lane & 2) << 3) | ((lane & 4) << 1) |
                  ((lane & 8) >> 1) | ((lane & 16) >> 3) | ((lane & 32) >> 5);

    __shared__ float redS[4][64];
    __shared__ float redl[4];
    __shared__ int   redc[4][CLS];
    const int wave = tid >> 6;

    redS[wave][e] = acc[0];
    const float lsum = wave_reduce(accl);
    if (lane == 0) {
        redl[wave] = lsum;
#pragma unroll
        for (int k = 0; k < CLS; ++k) redc[wave][k] = cnt[k];
    }
    __syncthreads();

    if (tid < 64) {
        const float v = redS[0][tid] + redS[1][tid] + redS[2][tid] + redS[3][tid];
        atomicAdd(&S[b * 64 + tid], v);
    } else if (tid < 64 + CLS) {
        const int k = tid - 64;
        const float v = (float)(redc[0][k] + redc[1][k] + redc[2][k] + redc[3][k]);
        atomicAdd(&nCnt[b * CLS + k], v);
    } else if (tid == 64 + CLS) {
        const float v = (redl[0] + redl[1] + redl[2] + redl[3]) * LN2;
        atomicAdd(lseAcc, v);
    }
}

// Epilogue: A = S/n; j[b] = -sum_{i!=k} w[i,k]*log(0.5+0.5*(A[i,i]-A[i,k]));
// ce = (sum(lse) - sum_b trace(S_b)) / (B*N);  out[b] = j[b] + ce
__global__ __launch_bounds__(64) void jce_final(
    const float* __restrict__ S, const float* __restrict__ nCnt,
    const float* __restrict__ lseAcc, const float* __restrict__ w,
    float* __restrict__ out, int N)
{
    const int b   = blockIdx.x;
    const int tid = threadIdx.x;           // 64 threads = (i,k)
    const int i = tid >> 3, k = tid & 7;

    const float A = S[b * 64 + tid] / nCnt[b * CLS + k];
    __shared__ float lA[64];
    lA[tid] = A;
    __syncthreads();
    const float diag = lA[i * 9];

    // trace over ALL batches of unnormalized S: tid -> (batch tid>>3, class tid&7)
    const float tv = S[(tid >> 3) * 64 + (tid & 7) * 9];

    float term = 0.f;
    if (i != k)
        term = w[tid] * (log2f(0.5f + 0.5f * (diag - A)) * LN2);

    const float termSum = wave_reduce(term);
    const float trAll   = wave_reduce(tv);

    if (tid == 0) {
        const float ce = (lseAcc[0] - trAll) / ((float)BATCH * (float)N);
        out[b] = -termSum + ce;
    }
}

extern "C" void kernel_launch(void* const* d_in, const int* in_sizes, int n_in,
                              void* d_out, int out_size, void* d_ws, size_t ws_size,
                              hipStream_t stream) {
    const float* pred = (const float*)d_in[0];
    const int*   tgt  = (const int*)d_in[1];
    const float* w    = (const float*)d_in[2];
    float* out = (float*)d_out;

    const int N = in_sizes[1] / BATCH;        // H*W = 262144

    float* S      = (float*)d_ws;             // BATCH*64
    float* nCnt   = S + BATCH * 64;           // BATCH*8
    float* lseAcc = nCnt + BATCH * CLS;       // 1

    hipMemsetAsync(d_ws, 0, (size_t)(BATCH * 64 + BATCH * CLS + 1) * sizeof(float), stream);

    jce_main<<<dim3(BATCH * BPB), dim3(256), 0, stream>>>(pred, tgt, S, nCnt, lseAcc, N);
    jce_final<<<dim3(BATCH), dim3(64), 0, stream>>>(S, nCnt, lseAcc, w, out, N);
}